// Round 11
// baseline (1274.281 us; speedup 1.0000x reference)
//
#include <hip/hip_runtime.h>

typedef unsigned short u16;
typedef unsigned int   u32;
typedef __bf16 bf16x8 __attribute__((ext_vector_type(8)));
typedef float  f32x4  __attribute__((ext_vector_type(4)));

#define DEV __device__ __forceinline__

DEV u16 f2bf(float f) {
    u32 u = __builtin_bit_cast(u32, f);
    u32 r = u + 0x7FFFu + ((u >> 16) & 1u);
    return (u16)(r >> 16);
}

DEV void gload16(const void* g, void* l) {
    __builtin_amdgcn_global_load_lds((const __attribute__((address_space(1))) void*)g,
                                     (__attribute__((address_space(3))) void*)l, 16, 0, 0);
}

// bijective XCD-aware swizzle (m204)
DEV int xcd_swz(int bid, int nwg) {
    int q = nwg >> 3, r = nwg & 7;
    int xcd = bid & 7, idx = bid >> 3;
    return (xcd < r ? xcd * (q + 1) : r * (q + 1) + (xcd - r) * q) + idx;
}

// involutive LDS byte swizzle for 128B rows: XOR byte bits[6:4] with row bits [0,2,1]
DEV int swz(int p) {
    int m = (((p >> 7) & 1) << 6) | (((p >> 9) & 1) << 5) | (((p >> 8) & 1) << 4);
    return p ^ m;
}

// pack 8 f32 -> 8 bf16 and store 16B
DEV void packwrite16(float4 a, float4 b, char* dst) {
    uint4 v;
    v.x = (u32)f2bf(a.x) | ((u32)f2bf(a.y) << 16);
    v.y = (u32)f2bf(a.z) | ((u32)f2bf(a.w) << 16);
    v.z = (u32)f2bf(b.x) | ((u32)f2bf(b.y) << 16);
    v.w = (u32)f2bf(b.z) | ((u32)f2bf(b.w) << 16);
    *(uint4*)dst = v;
}

// ---------------- convert f32 -> bf16 (single tensor) ----------------
__global__ void cvt_k(const float* __restrict__ src, u16* __restrict__ dst, int n4) {
    int i = blockIdx.x * blockDim.x + threadIdx.x;
    int stride = gridDim.x * blockDim.x;
    for (; i < n4; i += stride) {
        float4 v = ((const float4*)src)[i];
        ushort4 u;
        u.x = f2bf(v.x); u.y = f2bf(v.y); u.z = f2bf(v.z); u.w = f2bf(v.w);
        ((ushort4*)dst)[i] = u;
    }
}

// ---------------- LN core ----------------
DEV void ln_store(float4 v, const float* __restrict__ g, const float* __restrict__ b,
                  u16* __restrict__ out, int row, int t) {
    float s = v.x + v.y + v.z + v.w;
    float s2 = v.x * v.x + v.y * v.y + v.z * v.z + v.w * v.w;
    #pragma unroll
    for (int msk = 1; msk < 64; msk <<= 1) {
        s  += __shfl_xor(s, msk);
        s2 += __shfl_xor(s2, msk);
    }
    __shared__ float ps[4], ps2[4];
    if ((t & 63) == 0) { ps[t >> 6] = s; ps2[t >> 6] = s2; }
    __syncthreads();
    s = ps[0] + ps[1] + ps[2] + ps[3];
    s2 = ps2[0] + ps2[1] + ps2[2] + ps2[3];
    float mu = s * (1.0f / 1024.0f);
    float var = s2 * (1.0f / 1024.0f) - mu * mu;
    float rstd = rsqrtf(var + 1e-5f);
    float4 gg = ((const float4*)g)[t];
    float4 bb = ((const float4*)b)[t];
    ushort4 o;
    o.x = f2bf((v.x - mu) * rstd * gg.x + bb.x);
    o.y = f2bf((v.y - mu) * rstd * gg.y + bb.y);
    o.z = f2bf((v.z - mu) * rstd * gg.z + bb.z);
    o.w = f2bf((v.w - mu) * rstd * gg.w + bb.w);
    ((ushort4*)out)[(size_t)row * 256 + t] = o;
}

__global__ void ln_k(const float* __restrict__ in, const float* __restrict__ g,
                     const float* __restrict__ b, u16* __restrict__ out) {
    int row = blockIdx.x;
    int t = threadIdx.x;
    float4 v = ((const float4*)(in + (size_t)row * 1024))[t];
    ln_store(v, g, b, out, row, t);
}

__global__ void embed_ln_k(const int* __restrict__ x, const float* __restrict__ te,
                           const float* __restrict__ pe, float* __restrict__ h,
                           const float* __restrict__ g, const float* __restrict__ b,
                           u16* __restrict__ xn) {
    int row = blockIdx.x;
    int t = threadIdx.x;
    int tok = x[row];
    int s = row & 1023;
    float4 a = ((const float4*)(te + (size_t)tok * 1024))[t];
    float4 p = ((const float4*)(pe + (size_t)s * 1024))[t];
    a.x += p.x; a.y += p.y; a.z += p.z; a.w += p.w;
    ((float4*)(h + (size_t)row * 1024))[t] = a;
    ln_store(a, g, b, xn, row, t);
}

__global__ void fuse2ln_k(const float* __restrict__ p0, const float* __restrict__ p1,
                          const float* __restrict__ bias, float* __restrict__ h,
                          const float* __restrict__ g, const float* __restrict__ b,
                          u16* __restrict__ xn) {
    int row = blockIdx.x;
    int t = threadIdx.x;
    size_t idx = (size_t)row * 256 + t;
    float4 a = ((const float4*)p0)[idx];
    float4 bb = ((const float4*)p1)[idx];
    float4 c = ((const float4*)bias)[t];
    float4 v = ((const float4*)h)[idx];
    v.x += a.x + bb.x + c.x;
    v.y += a.y + bb.y + c.y;
    v.z += a.z + bb.z + c.z;
    v.w += a.w + bb.w + c.w;
    ((float4*)h)[idx] = v;
    ln_store(v, g, b, xn, row, t);
}

// ============ 256x256 8-wave 4-phase-per-K-tile GEMM (BK=64, counted vmcnt) ============
template<int PH>
DEV void phase_mma(const bf16x8 (&af)[2][2], const bf16x8 (&bfr)[4][2], f32x4 (&acc)[8][4]) {
    __builtin_amdgcn_s_barrier();
    asm volatile("s_waitcnt lgkmcnt(0)" ::: "memory");
    __builtin_amdgcn_sched_barrier(0);
    __builtin_amdgcn_s_setprio(1);
    #pragma unroll
    for (int ms = 0; ms < 2; ++ms)
        #pragma unroll
        for (int nj = 0; nj < 4; ++nj)
            #pragma unroll
            for (int kk = 0; kk < 2; ++kk)
                acc[PH * 2 + ms][nj] = __builtin_amdgcn_mfma_f32_16x16x32_bf16(
                    af[ms][kk], bfr[nj][kk], acc[PH * 2 + ms][nj], 0, 0, 0);
    __builtin_amdgcn_s_setprio(0);
}

template<int PH>
DEV void read_afrags(const char* Ab, int arow, int fr, int fq, bf16x8 (&af)[2][2]) {
    #pragma unroll
    for (int ms = 0; ms < 2; ++ms)
        #pragma unroll
        for (int kk = 0; kk < 2; ++kk) {
            int lin = (arow + (PH * 2 + ms) * 16 + fr) * 128 + kk * 64 + fq * 16;
            af[ms][kk] = *(const bf16x8*)(Ab + swz(lin));
        }
}

template<int BIAS, int OUTBF>
__global__ __launch_bounds__(512, 2)
void gemm8p(const u16* __restrict__ A, const u16* __restrict__ Bw,
            const float* __restrict__ bias,
            float* __restrict__ outf, u16* __restrict__ outb,
            int M, int N, int K) {
    __shared__ char lds[131072];
    char* ldsA = lds;
    char* ldsB = lds + 65536;
    const int t = threadIdx.x;
    const int w = t >> 6, l = t & 63;
    const int fr = l & 15, fq = l >> 4;
    const int wm = w >> 2, wn = w & 3;

    int bid = blockIdx.y * gridDim.x + blockIdx.x;
    int swzb = xcd_swz(bid, gridDim.x * gridDim.y);
    const int m0 = (swzb % gridDim.x) * 256;
    const int n0 = (swzb / gridDim.x) * 256;
    const int nt = K >> 6;
    const int arow = wm * 128;

    const u16* Asrc = A + (size_t)m0 * K;
    const u16* Bsrc = Bw + (size_t)n0 * K;

    size_t o00, o01, o10, o11;
    {
        int p;
        p = 0 * 16384 + 0 * 8192 + t * 16; o00 = (size_t)(p >> 7) * K + ((swz(p) & 127) >> 1);
        p = 0 * 16384 + 1 * 8192 + t * 16; o01 = (size_t)(p >> 7) * K + ((swz(p) & 127) >> 1);
        p = 1 * 16384 + 0 * 8192 + t * 16; o10 = (size_t)(p >> 7) * K + ((swz(p) & 127) >> 1);
        p = 1 * 16384 + 1 * 8192 + t * 16; o11 = (size_t)(p >> 7) * K + ((swz(p) & 127) >> 1);
    }
    const int wb = w * 1024;

    gload16(Asrc + o00, ldsA + wb);
    gload16(Asrc + o01, ldsA + 8192 + wb);
    gload16(Asrc + o10, ldsA + 16384 + wb);
    gload16(Asrc + o11, ldsA + 16384 + 8192 + wb);
    gload16(Bsrc + o00, ldsB + wb);
    gload16(Bsrc + o01, ldsB + 8192 + wb);
    gload16(Bsrc + o10, ldsB + 16384 + wb);
    gload16(Bsrc + o11, ldsB + 16384 + 8192 + wb);
    gload16(Bsrc + o00 + 64, ldsB + 32768 + wb);
    gload16(Bsrc + o01 + 64, ldsB + 32768 + 8192 + wb);
    gload16(Bsrc + o10 + 64, ldsB + 32768 + 16384 + wb);
    gload16(Bsrc + o11 + 64, ldsB + 32768 + 16384 + 8192 + wb);
    asm volatile("s_waitcnt vmcnt(4)" ::: "memory");
    __builtin_amdgcn_s_barrier();
    __builtin_amdgcn_sched_barrier(0);

    f32x4 acc[8][4] = {};

    for (int T = 0; T < nt; ++T) {
        const char* Ab = ldsA + (T & 1) * 32768;
        const char* Bb = ldsB + (T & 1) * 32768;
        char* Anx = ldsA + ((T + 1) & 1) * 32768;
        char* Bnx = ldsB + (T & 1) * 32768;
        const bool stA = (T + 1 < nt), stB = (T + 2 < nt);
        const size_t kA = (size_t)(T + 1) * 64, kB = (size_t)(T + 2) * 64;

        bf16x8 bfr[4][2], af[2][2];

        #pragma unroll
        for (int nj = 0; nj < 4; ++nj)
            #pragma unroll
            for (int kk = 0; kk < 2; ++kk) {
                int lin = (wn * 64 + nj * 16 + fr) * 128 + kk * 64 + fq * 16;
                bfr[nj][kk] = *(const bf16x8*)(Bb + swz(lin));
            }
        read_afrags<0>(Ab, arow, fr, fq, af);
        if (stA) {
            gload16(Asrc + o00 + kA, Anx + wb);
            gload16(Asrc + o01 + kA, Anx + 8192 + wb);
        }
        phase_mma<0>(af, bfr, acc);
        __builtin_amdgcn_s_barrier();

        read_afrags<1>(Ab, arow, fr, fq, af);
        if (stA) {
            gload16(Asrc + o10 + kA, Anx + 16384 + wb);
            gload16(Asrc + o11 + kA, Anx + 16384 + 8192 + wb);
        }
        phase_mma<1>(af, bfr, acc);
        __builtin_amdgcn_s_barrier();

        read_afrags<2>(Ab, arow, fr, fq, af);
        if (stB) {
            gload16(Bsrc + o00 + kB, Bnx + wb);
            gload16(Bsrc + o01 + kB, Bnx + 8192 + wb);
        }
        phase_mma<2>(af, bfr, acc);
        __builtin_amdgcn_s_barrier();

        read_afrags<3>(Ab, arow, fr, fq, af);
        if (stB) {
            gload16(Bsrc + o10 + kB, Bnx + 16384 + wb);
            gload16(Bsrc + o11 + kB, Bnx + 16384 + 8192 + wb);
        }
        phase_mma<3>(af, bfr, acc);
        if (stB)      asm volatile("s_waitcnt vmcnt(4)" ::: "memory");
        else if (stA) asm volatile("s_waitcnt vmcnt(0)" ::: "memory");
        __builtin_amdgcn_s_barrier();
        __builtin_amdgcn_sched_barrier(0);
    }

    #pragma unroll
    for (int mi = 0; mi < 8; ++mi) {
        #pragma unroll
        for (int nj = 0; nj < 4; ++nj) {
            #pragma unroll
            for (int r = 0; r < 4; ++r) {
                int row = m0 + wm * 128 + mi * 16 + fq * 4 + r;
                int col = n0 + wn * 64 + nj * 16 + fr;
                float v = acc[mi][nj][r];
                if (BIAS) v += bias[col];
                if (OUTBF) outb[(size_t)row * N + col] = f2bf(v);
                else       outf[(size_t)row * N + col] = v;
            }
        }
    }
}

// ============ 128x128 8-wave 2-phase GEMM with DIRECT f32 B (reg-staged, counted vmcnt) ============
// A: bf16 via global_load_lds (pre-swizzled source). B: f32 weights loaded to regs,
// converted, ds_write'd swizzled. Steady-state: B(T+1) regs loaded at T-1.ph1;
// T.ph1: vmcnt(2) -> ds_write B(T+1) -> issue B(T+2) loads. Boundary: vmcnt(4).
template<int BIAS, int GELU_, int OUTBF, int SPLITK>
__global__ __launch_bounds__(512, 2)
void gemm4pf(const u16* __restrict__ A, const float* __restrict__ Bw32,
             const float* __restrict__ bias,
             float* __restrict__ outf, u16* __restrict__ outb,
             int M, int N, int K) {
    __shared__ char lds[65536];
    char* ldsA = lds;            // 2 x 16384
    char* ldsB = lds + 32768;    // 2 x 16384
    const int t = threadIdx.x;
    const int w = t >> 6, l = t & 63;
    const int fr = l & 15, fq = l >> 4;
    const int wm = w >> 2, wn = w & 3;

    int bid = blockIdx.y * gridDim.x + blockIdx.x;
    int swzb = xcd_swz(bid, gridDim.x * gridDim.y);
    const int m0 = (swzb % gridDim.x) * 128;
    const int n0 = (swzb / gridDim.x) * 128;

    int kbase = 0, Keff = K;
    if (SPLITK) { Keff = K >> 1; kbase = blockIdx.z * Keff; }
    const int nt = Keff >> 6;

    const u16* Asrc = A + (size_t)m0 * K + kbase;

    // A staging offsets (pre-swizzled source, linear LDS dest)
    size_t o0, o1;
    {
        int p = t * 16;        o0 = (size_t)(p >> 7) * K + ((swz(p) & 127) >> 1);
        p = 8192 + t * 16;     o1 = (size_t)(p >> 7) * K + ((swz(p) & 127) >> 1);
    }
    const int wb = w * 1024;

    // B staging: thread owns logical bytes p0=t*16 and p1=8192+t*16 (8 bf16 each)
    const int p0 = t * 16, p1 = 8192 + t * 16;
    const int q0s = swz(p0), q1s = swz(p1);     // swizzled LDS offsets within buffer
    const float* Bs0 = Bw32 + (size_t)(n0 + (p0 >> 7)) * K + kbase + ((p0 & 127) >> 1);
    const float* Bs1 = Bw32 + (size_t)(n0 + (p1 >> 7)) * K + kbase + ((p1 & 127) >> 1);

    float4 rb0, rb1, rb2, rb3;   // B regs: 16 f32

    // prologue
    rb0 = *(const float4*)(Bs0);     rb1 = *(const float4*)(Bs0 + 4);
    rb2 = *(const float4*)(Bs1);     rb3 = *(const float4*)(Bs1 + 4);
    gload16(Asrc + o0, ldsA + wb);
    gload16(Asrc + o1, ldsA + 8192 + wb);
    asm volatile("s_waitcnt vmcnt(2)" ::: "memory");    // B(0) regs landed
    packwrite16(rb0, rb1, ldsB + q0s);
    packwrite16(rb2, rb3, ldsB + q1s);
    if (nt > 1) {
        rb0 = *(const float4*)(Bs0 + 64);  rb1 = *(const float4*)(Bs0 + 68);
        rb2 = *(const float4*)(Bs1 + 64);  rb3 = *(const float4*)(Bs1 + 68);
    }
    asm volatile("s_waitcnt vmcnt(4) lgkmcnt(0)" ::: "memory");  // A(0) landed, B(0) writes retired
    __builtin_amdgcn_s_barrier();
    __builtin_amdgcn_sched_barrier(0);
    // state: regs hold B(1) (in flight x4); nothing else outstanding except those.

    f32x4 acc[4][2] = {};

    for (int T = 0; T < nt; ++T) {
        const char* Ab = ldsA + (T & 1) * 16384;
        const char* Bb = ldsB + (T & 1) * 16384;
        char* Anx = ldsA + ((T + 1) & 1) * 16384;
        char* Bnx = ldsB + ((T + 1) & 1) * 16384;
        const bool stA = (T + 1 < nt), stB = (T + 2 < nt);
        const size_t kA = (size_t)(T + 1) * 64;
        const size_t kB = (size_t)(T + 2) * 64;

        bf16x8 bfr[2][2], af[2][2];

        // ---- phase 0: B(T)+A(T)01 frags; issue gloadA(T+1) ----
        #pragma unroll
        for (int nj = 0; nj < 2; ++nj)
            #pragma unroll
            for (int kk = 0; kk < 2; ++kk) {
                int lin = (wn * 32 + nj * 16 + fr) * 128 + kk * 64 + fq * 16;
                bfr[nj][kk] = *(const bf16x8*)(Bb + swz(lin));
            }
        #pragma unroll
        for (int ms = 0; ms < 2; ++ms)
            #pragma unroll
            for (int kk = 0; kk < 2; ++kk) {
                int lin = (wm * 64 + ms * 16 + fr) * 128 + kk * 64 + fq * 16;
                af[ms][kk] = *(const bf16x8*)(Ab + swz(lin));
            }
        if (stA) {
            gload16(Asrc + o0 + kA, Anx + wb);
            gload16(Asrc + o1 + kA, Anx + 8192 + wb);
        }
        __builtin_amdgcn_s_barrier();
        asm volatile("s_waitcnt lgkmcnt(0)" ::: "memory");
        __builtin_amdgcn_sched_barrier(0);
        __builtin_amdgcn_s_setprio(1);
        #pragma unroll
        for (int ms = 0; ms < 2; ++ms)
            #pragma unroll
            for (int nj = 0; nj < 2; ++nj)
                #pragma unroll
                for (int kk = 0; kk < 2; ++kk)
                    acc[ms][nj] = __builtin_amdgcn_mfma_f32_16x16x32_bf16(
                        af[ms][kk], bfr[nj][kk], acc[ms][nj], 0, 0, 0);
        __builtin_amdgcn_s_setprio(0);
        __builtin_amdgcn_s_barrier();

        // ---- phase 1: A(T)23 frags; write B(T+1); issue B(T+2) loads; boundary vmcnt ----
        #pragma unroll
        for (int ms = 0; ms < 2; ++ms)
            #pragma unroll
            for (int kk = 0; kk < 2; ++kk) {
                int lin = (wm * 64 + (2 + ms) * 16 + fr) * 128 + kk * 64 + fq * 16;
                af[ms][kk] = *(const bf16x8*)(Ab + swz(lin));
            }
        if (stA) {
            // B(T+1) regs landed? outstanding: [B(T+1) x4 (oldest), A(T+1) x2]
            asm volatile("s_waitcnt vmcnt(2)" ::: "memory");
            packwrite16(rb0, rb1, Bnx + q0s);
            packwrite16(rb2, rb3, Bnx + q1s);
            if (stB) {
                rb0 = *(const float4*)(Bs0 + kB);      rb1 = *(const float4*)(Bs0 + kB + 4);
                rb2 = *(const float4*)(Bs1 + kB);      rb3 = *(const float4*)(Bs1 + kB + 4);
            }
        }
        __builtin_amdgcn_s_barrier();
        asm volatile("s_waitcnt lgkmcnt(0)" ::: "memory");
        __builtin_amdgcn_sched_barrier(0);
        __builtin_amdgcn_s_setprio(1);
        #pragma unroll
        for (int ms = 0; ms < 2; ++ms)
            #pragma unroll
            for (int nj = 0; nj < 2; ++nj)
                #pragma unroll
                for (int kk = 0; kk < 2; ++kk)
                    acc[2 + ms][nj] = __builtin_amdgcn_mfma_f32_16x16x32_bf16(
                        af[ms][kk], bfr[nj][kk], acc[2 + ms][nj], 0, 0, 0);
        __builtin_amdgcn_s_setprio(0);
        // boundary: need A(T+1) landed; B(T+2) loads (newest 4) may stay in flight
        if (stB)      asm volatile("s_waitcnt vmcnt(4)" ::: "memory");
        else if (stA) asm volatile("s_waitcnt vmcnt(0)" ::: "memory");
        __builtin_amdgcn_s_barrier();
        __builtin_amdgcn_sched_barrier(0);
    }

    float* op = outf;
    if (SPLITK) op = outf + (size_t)blockIdx.z * M * N;

    #pragma unroll
    for (int mi = 0; mi < 4; ++mi) {
        #pragma unroll
        for (int nj = 0; nj < 2; ++nj) {
            #pragma unroll
            for (int r = 0; r < 4; ++r) {
                int row = m0 + wm * 64 + mi * 16 + fq * 4 + r;
                int col = n0 + wn * 32 + nj * 16 + fr;
                float v = acc[mi][nj][r];
                if (BIAS) v += bias[col];
                if (GELU_) v = 0.5f * v * (1.0f + erff(v * 0.70710678118f));
                if (OUTBF) outb[(size_t)row * N + col] = f2bf(v);
                else       op[(size_t)row * N + col] = v;
            }
        }
    }
}

// ---------------- 2-phase double-buffered GEMM (proj: RES epilogue) ----------------
template<int BM, int BN, int BIAS, int GELU_, int RES, int OUTBF, int SPLITK>
__global__ void gemm_db(const u16* __restrict__ A, const u16* __restrict__ Bw,
                        const float* __restrict__ bias, const float* __restrict__ res,
                        float* __restrict__ outf, u16* __restrict__ outb,
                        int M, int N, int K) {
    constexpr int MR = BM / 32;
    constexpr int NR = BN / 32;
    constexpr int AL = BM / 64;
    constexpr int BL = BN / 64;
    __shared__ u16 lA[2][BM * 32];
    __shared__ u16 lB[2][BN * 32];
    const int t = threadIdx.x;
    const int w = t >> 6, l = t & 63;

    int bid = blockIdx.y * gridDim.x + blockIdx.x;
    int swzb = xcd_swz(bid, gridDim.x * gridDim.y);
    const int m0 = (swzb % gridDim.x) * BM;
    const int n0 = (swzb / gridDim.x) * BN;

    int kbase = 0, Keff = K;
    if (SPLITK) { Keff = K >> 1; kbase = blockIdx.z * Keff; }
    const int nt = Keff >> 5;

    const int wr = (w >> 1) * (BM / 2), wc = (w & 1) * (BN / 2);
    const int fr = l & 15, fq = l >> 4;
    const int g0 = w * 64 + l;

    const int srow = g0 >> 2, scol = (g0 & 3) * 8;

    f32x4 acc[MR][NR] = {};

    #pragma unroll
    for (int i = 0; i < AL; ++i)
        gload16(A + (size_t)(m0 + srow + i * 64) * K + kbase + scol, lA[0] + (srow + i * 64) * 32 + scol);
    #pragma unroll
    for (int i = 0; i < BL; ++i)
        gload16(Bw + (size_t)(n0 + srow + i * 64) * K + kbase + scol, lB[0] + (srow + i * 64) * 32 + scol);
    __syncthreads();

    for (int T = 0; T < nt; ++T) {
        const int cur = T & 1, nxt = cur ^ 1;
        if (T + 1 < nt) {
            const int kk = kbase + (T + 1) * 32;
            #pragma unroll
            for (int i = 0; i < AL; ++i)
                gload16(A + (size_t)(m0 + srow + i * 64) * K + kk + scol, lA[nxt] + (srow + i * 64) * 32 + scol);
            #pragma unroll
            for (int i = 0; i < BL; ++i)
                gload16(Bw + (size_t)(n0 + srow + i * 64) * K + kk + scol, lB[nxt] + (srow + i * 64) * 32 + scol);
        }
        bf16x8 af[MR], bfv[NR];
        #pragma unroll
        for (int mi = 0; mi < MR; ++mi)
            af[mi] = *(const bf16x8*)(lA[cur] + (wr + mi * 16 + fr) * 32 + fq * 8);
        #pragma unroll
        for (int ni = 0; ni < NR; ++ni)
            bfv[ni] = *(const bf16x8*)(lB[cur] + (wc + ni * 16 + fr) * 32 + fq * 8);
        #pragma unroll
        for (int mi = 0; mi < MR; ++mi)
            #pragma unroll
            for (int ni = 0; ni < NR; ++ni)
                acc[mi][ni] = __builtin_amdgcn_mfma_f32_16x16x32_bf16(af[mi], bfv[ni], acc[mi][ni], 0, 0, 0);
        __syncthreads();
    }

    float* op = outf;
    if (SPLITK) op = outf + (size_t)blockIdx.z * M * N;

    #pragma unroll
    for (int mi = 0; mi < MR; ++mi) {
        #pragma unroll
        for (int ni = 0; ni < NR; ++ni) {
            #pragma unroll
            for (int r = 0; r < 4; ++r) {
                int row = m0 + wr + mi * 16 + fq * 4 + r;
                int col = n0 + wc + ni * 16 + fr;
                float v = acc[mi][ni][r];
                if (BIAS) v += bias[col];
                if (GELU_) v = 0.5f * v * (1.0f + erff(v * 0.70710678118f));
                if (RES) v += res[(size_t)row * N + col];
                if (OUTBF) outb[(size_t)row * N + col] = f2bf(v);
                else       op[(size_t)row * N + col] = v;
            }
        }
    }
}

// ---------------- Flash attention: QBLK=128, 8 waves, async V prefetch ----------------
__global__ __launch_bounds__(512, 2)
void attn_k(const u16* __restrict__ qkv, u16* __restrict__ o) {
    __shared__ u16 lK[64 * 64];
    __shared__ u16 lV[64 * 64];
    __shared__ u16 lP[8 * 16 * 64];
    const int t = threadIdx.x;
    const int w = t >> 6, l = t & 63;
    const int fr = l & 15, fq = l >> 4;

    int swzb = xcd_swz(blockIdx.x, gridDim.x);
    const int qb = 7 - (swzb & 7);
    const int hh = (swzb >> 3) & 15;
    const int b  = swzb >> 7;
    const int q0 = qb * 128;
    const int qw = q0 + w * 16;

    const u16* srcK;
    {
        int p = t * 16;
        int L = swz(p);
        srcK = qkv + ((size_t)(b * 1024) + (L >> 7)) * 3072 + 1024 + hh * 64 + ((L & 127) >> 1);
    }

    const int kvp = (t & 31) * 2;
    const int vd0 = (t >> 5) * 4;
    const u16* srcV = qkv + (size_t)(b * 1024) * 3072 + 2048 + hh * 64 + vd0;

    bf16x8 qf[2];
    {
        size_t base = ((size_t)(b * 1024) + qw + fr) * 3072 + hh * 64;
        qf[0] = *(const bf16x8*)(qkv + base + fq * 8);
        qf[1] = *(const bf16x8*)(qkv + base + 32 + fq * 8);
    }

    float m_run[4], l_run[4];
    f32x4 acc_o[4] = {};
    #pragma unroll
    for (int r = 0; r < 4; ++r) { m_run[r] = -__builtin_inff(); l_run[r] = 0.0f; }

    uint2 gv0 = *(const uint2*)(srcV + (size_t)kvp * 3072);
    uint2 gv1 = *(const uint2*)(srcV + (size_t)(kvp + 1) * 3072);

    const int kv_end = q0 + 128;
    for (int kv0 = 0; kv0 < kv_end; kv0 += 64) {
        #pragma unroll
        for (int j = 0; j < 4; ++j) {
            u32 lo = (j < 2) ? gv0.x : gv0.y;
            u32 hi = (j < 2) ? gv1.x : gv1.y;
            lo = (j & 1) ? (lo >> 16) : (lo & 0xffffu);
            hi = (j & 1) ? (hi >> 16) : (hi & 0xffffu);
            u32 word = lo | (hi << 16);
            int pv = (vd0 + j) * 128 + kvp * 2;
            *(u32*)((char*)lV + swz(pv)) = word;
        }
        gload16(srcK + (size_t)kv0 * 3072, (char*)lK + w * 1024);
        __syncthreads();

        if (kv0 + 64 < kv_end) {
            gv0 = *(const uint2*)(srcV + (size_t)(kv0 + 64 + kvp) * 3072);
            gv1 = *(const uint2*)(srcV + (size_t)(kv0 + 64 + kvp + 1) * 3072);
        }

        const bool active = (kv0 <= qw + 15);
        if (active) {
            f32x4 accs[4] = {};
            #pragma unroll
            for (int nt = 0; nt < 4; ++nt) {
                #pragma unroll
                for (int ks = 0; ks < 2; ++ks) {
                    int pk = ((nt * 16 + fr) * 64 + ks * 32 + fq * 8) * 2;
                    bf16x8 kf = *(const bf16x8*)((const char*)lK + swz(pk));
                    accs[nt] = __builtin_amdgcn_mfma_f32_16x16x32_bf16(qf[ks], kf, accs[nt], 0, 0, 0);
                }
            }

            float p[4][4], mx[4], rs[4];
            #pragma unroll
            for (int r = 0; r < 4; ++r) {
                int qg = qw + fq * 4 + r;
                float m = -__builtin_inff();
                #pragma unroll
                for (int nt = 0; nt < 4; ++nt) {
                    int kvg = kv0 + nt * 16 + fr;
                    float s = (kvg <= qg) ? accs[nt][r] * 0.125f : -__builtin_inff();
                    p[nt][r] = s;
                    m = fmaxf(m, s);
                }
                mx[r] = m;
            }
            #pragma unroll
            for (int msk = 1; msk < 16; msk <<= 1) {
                #pragma unroll
                for (int r = 0; r < 4; ++r) mx[r] = fmaxf(mx[r], __shfl_xor(mx[r], msk));
            }
            float mnew[4], alpha[4];
            #pragma unroll
            for (int r = 0; r < 4; ++r) {
                mnew[r] = fmaxf(m_run[r], mx[r]);
                alpha[r] = __expf(m_run[r] - mnew[r]);
                float s = 0.0f;
                #pragma unroll
                for (int nt = 0; nt < 4; ++nt) {
                    float pv = __expf(p[nt][r] - mnew[r]);
                    p[nt][r] = pv;
                    s += pv;
                }
                rs[r] = s;
            }
            #pragma unroll
            for (int msk = 1; msk < 16; msk <<= 1) {
                #pragma unroll
                for (int r = 0; r < 4; ++r) rs[r] += __shfl_xor(rs[r], msk);
            }
            #pragma unroll
            for (int r = 0; r < 4; ++r) {
                l_run[r] = l_run[r] * alpha[r] + rs[r];
                m_run[r] = mnew[r];
            }
            #pragma unroll
            for (int nt = 0; nt < 4; ++nt)
                #pragma unroll
                for (int r = 0; r < 4; ++r) acc_o[nt][r] *= alpha[r];

            #pragma unroll
            for (int nt = 0; nt < 4; ++nt)
                #pragma unroll
                for (int r = 0; r < 4; ++r) {
                    int pp = (w * 1024 + (fq * 4 + r) * 64 + nt * 16 + fr) * 2;
                    *(u16*)((char*)lP + swz(pp)) = f2bf(p[nt][r]);
                }

            bf16x8 pa[2];
            #pragma unroll
            for (int ks = 0; ks < 2; ++ks) {
                int ppr = (w * 1024 + fr * 64 + ks * 32 + fq * 8) * 2;
                pa[ks] = *(const bf16x8*)((const char*)lP + swz(ppr));
            }
            #pragma unroll
            for (int nt = 0; nt < 4; ++nt) {
                #pragma unroll
                for (int ks = 0; ks < 2; ++ks) {
                    int pvr = ((nt * 16 + fr) * 64 + ks * 32 + fq * 8) * 2;
                    bf16x8 vf = *(const bf16x8*)((const char*)lV + swz(pvr));
                    acc_o[nt] = __builtin_amdgcn_mfma_f32_16x16x32_bf16(pa[ks], vf, acc_o[nt], 0, 0, 0);
                }
            }
        }
        __syncthreads();
    }

    #pragma unroll
    for (int nt = 0; nt < 4; ++nt) {
        #pragma unroll
        for (int r = 0; r < 4; ++r) {
            int qg = qw + fq * 4 + r;
            int d = nt * 16 + fr;
            float ov = acc_o[nt][r] / l_run[r];
            o[((size_t)(b * 1024) + qg) * 1024 + hh * 64 + d] = f2bf(ov);
        }
    }
}

// ---------------- launch ----------------
extern "C" void kernel_launch(void* const* d_in, const int* in_sizes, int n_in,
                              void* d_out, int out_size, void* d_ws, size_t ws_size,
                              hipStream_t stream) {
    const int*   x       = (const int*)  d_in[0];
    const float* tok_emb = (const float*)d_in[1];
    const float* pos_emb = (const float*)d_in[2];
    const float* ln1_g   = (const float*)d_in[3];
    const float* ln1_b   = (const float*)d_in[4];
    const float* qkv_w   = (const float*)d_in[5];
    const float* qkv_b   = (const float*)d_in[6];
    const float* proj_w  = (const float*)d_in[7];
    const float* proj_b  = (const float*)d_in[8];
    const float* ln2_g   = (const float*)d_in[9];
    const float* ln2_b   = (const float*)d_in[10];
    const float* fc1_w   = (const float*)d_in[11];
    const float* fc1_b   = (const float*)d_in[12];
    const float* fc2_w   = (const float*)d_in[13];
    const float* fc2_b   = (const float*)d_in[14];
    const float* lnf_g   = (const float*)d_in[15];
    const float* lnf_b   = (const float*)d_in[16];
    const float* head_w  = (const float*)d_in[17];
    float* out = (float*)d_out;

    char* ws = (char*)d_ws;
    float* h   = (float*)(ws + 0);            //  8 MB f32 (2048x1024)
    u16*   xn  = (u16*)(ws + 8388608);        //  4 MB bf16
    u16*   qkv = (u16*)(ws + 12582912);       // 12.6 MB bf16 (2048x3072)
    u16*   ob  = (u16*)(ws + 25165824);       //  4 MB bf16
    u16*   ff  = (u16*)(ws + 29360128);       // 16.8 MB bf16 (2048x4096)
    u16*   wq  = (u16*)(ws + 46137344);       // 65.5 MB bf16 slab (head weights; proj at front)
    float* pbuf = (float*)(ws + 12582912);    // fc2 split-K partials (dead region)

    const int M = 2048;

    embed_ln_k<<<dim3(2048), 256, 0, stream>>>(x, tok_emb, pos_emb, h, ln1_g, ln1_b, xn);

    for (int lyr = 0; lyr < 6; ++lyr) {
        // proj weights only: tiny bf16 convert (4 MB read, 2 MB write)
        cvt_k<<<dim3(512), 256, 0, stream>>>(proj_w + (size_t)lyr * 1024 * 1024, wq, 1024 * 1024 / 4);
        gemm4pf<1, 0, 1, 0><<<dim3(16, 24), 512, 0, stream>>>(
            xn, qkv_w + (size_t)lyr * 3072 * 1024, qkv_b + lyr * 3072, nullptr, qkv, M, 3072, 1024);
        attn_k<<<dim3(256), 512, 0, stream>>>(qkv, ob);
        gemm_db<64, 64, 1, 0, 1, 0, 0><<<dim3(32, 16), 256, 0, stream>>>(
            ob, wq, proj_b + lyr * 1024, h, h, nullptr, M, 1024, 1024);
        ln_k<<<dim3(2048), 256, 0, stream>>>(h, ln2_g + lyr * 1024, ln2_b + lyr * 1024, xn);
        gemm4pf<1, 1, 1, 0><<<dim3(16, 32), 512, 0, stream>>>(
            xn, fc1_w + (size_t)lyr * 4096 * 1024, fc1_b + lyr * 4096, nullptr, ff, M, 4096, 1024);
        gemm4pf<0, 0, 0, 1><<<dim3(16, 8, 2), 512, 0, stream>>>(
            ff, fc2_w + (size_t)lyr * 1024 * 4096, nullptr, pbuf, nullptr, M, 1024, 4096);
        const float* g = (lyr < 5) ? (ln1_g + (lyr + 1) * 1024) : lnf_g;
        const float* b = (lyr < 5) ? (ln1_b + (lyr + 1) * 1024) : lnf_b;
        fuse2ln_k<<<dim3(2048), 256, 0, stream>>>(
            pbuf, pbuf + (size_t)M * 1024, fc2_b + lyr * 1024, h, g, b, xn);
    }

    cvt_k<<<dim3(2048), 256, 0, stream>>>(head_w, wq, 32000 * 1024 / 4);
    gemm8p<0, 0><<<dim3(8, 125), 512, 0, stream>>>(
        xn, wq, nullptr, out, nullptr, M, 32000, 1024);
}

// Round 12
// 1192.655 us; speedup vs baseline: 1.0684x; 1.0684x over previous
//
#include <hip/hip_runtime.h>

typedef unsigned short u16;
typedef unsigned int   u32;
typedef __bf16 bf16x8 __attribute__((ext_vector_type(8)));
typedef float  f32x4  __attribute__((ext_vector_type(4)));

#define DEV __device__ __forceinline__

DEV u16 f2bf(float f) {
    u32 u = __builtin_bit_cast(u32, f);
    u32 r = u + 0x7FFFu + ((u >> 16) & 1u);
    return (u16)(r >> 16);
}

DEV void gload16(const void* g, void* l) {
    __builtin_amdgcn_global_load_lds((const __attribute__((address_space(1))) void*)g,
                                     (__attribute__((address_space(3))) void*)l, 16, 0, 0);
}

// bijective XCD-aware swizzle (m204)
DEV int xcd_swz(int bid, int nwg) {
    int q = nwg >> 3, r = nwg & 7;
    int xcd = bid & 7, idx = bid >> 3;
    return (xcd < r ? xcd * (q + 1) : r * (q + 1) + (xcd - r) * q) + idx;
}

// involutive LDS byte swizzle for 128B rows: XOR byte bits[6:4] with row bits [0,2,1]
DEV int swz(int p) {
    int m = (((p >> 7) & 1) << 6) | (((p >> 9) & 1) << 5) | (((p >> 8) & 1) << 4);
    return p ^ m;
}

// ---------------- convert f32 -> bf16 (single tensor) ----------------
__global__ void cvt_k(const float* __restrict__ src, u16* __restrict__ dst, int n4) {
    int i = blockIdx.x * blockDim.x + threadIdx.x;
    int stride = gridDim.x * blockDim.x;
    for (; i < n4; i += stride) {
        float4 v = ((const float4*)src)[i];
        ushort4 u;
        u.x = f2bf(v.x); u.y = f2bf(v.y); u.z = f2bf(v.z); u.w = f2bf(v.w);
        ((ushort4*)dst)[i] = u;
    }
}

// ---------------- convert 4 tensors in one launch (per-layer weights) ----------------
__global__ void cvt4_k(const float* __restrict__ s0, const float* __restrict__ s1,
                       const float* __restrict__ s2, const float* __restrict__ s3,
                       u16* __restrict__ dst, int n0, int n1, int n2, int n3) {
    int i = blockIdx.x * blockDim.x + threadIdx.x;
    int stride = gridDim.x * blockDim.x;
    int t0 = n0, t1 = t0 + n1, t2 = t1 + n2, t3 = t2 + n3;
    for (; i < t3; i += stride) {
        const float* s; int j;
        if (i < t0)      { s = s0; j = i; }
        else if (i < t1) { s = s1; j = i - t0; }
        else if (i < t2) { s = s2; j = i - t1; }
        else             { s = s3; j = i - t2; }
        float4 v = ((const float4*)s)[j];
        ushort4 u;
        u.x = f2bf(v.x); u.y = f2bf(v.y); u.z = f2bf(v.z); u.w = f2bf(v.w);
        ((ushort4*)dst)[i] = u;
    }
}

// ---------------- LN core ----------------
DEV void ln_store(float4 v, const float* __restrict__ g, const float* __restrict__ b,
                  u16* __restrict__ out, int row, int t) {
    float s = v.x + v.y + v.z + v.w;
    float s2 = v.x * v.x + v.y * v.y + v.z * v.z + v.w * v.w;
    #pragma unroll
    for (int msk = 1; msk < 64; msk <<= 1) {
        s  += __shfl_xor(s, msk);
        s2 += __shfl_xor(s2, msk);
    }
    __shared__ float ps[4], ps2[4];
    if ((t & 63) == 0) { ps[t >> 6] = s; ps2[t >> 6] = s2; }
    __syncthreads();
    s = ps[0] + ps[1] + ps[2] + ps[3];
    s2 = ps2[0] + ps2[1] + ps2[2] + ps2[3];
    float mu = s * (1.0f / 1024.0f);
    float var = s2 * (1.0f / 1024.0f) - mu * mu;
    float rstd = rsqrtf(var + 1e-5f);
    float4 gg = ((const float4*)g)[t];
    float4 bb = ((const float4*)b)[t];
    ushort4 o;
    o.x = f2bf((v.x - mu) * rstd * gg.x + bb.x);
    o.y = f2bf((v.y - mu) * rstd * gg.y + bb.y);
    o.z = f2bf((v.z - mu) * rstd * gg.z + bb.z);
    o.w = f2bf((v.w - mu) * rstd * gg.w + bb.w);
    ((ushort4*)out)[(size_t)row * 256 + t] = o;
}

__global__ void ln_k(const float* __restrict__ in, const float* __restrict__ g,
                     const float* __restrict__ b, u16* __restrict__ out) {
    int row = blockIdx.x;
    int t = threadIdx.x;
    float4 v = ((const float4*)(in + (size_t)row * 1024))[t];
    ln_store(v, g, b, out, row, t);
}

__global__ void embed_ln_k(const int* __restrict__ x, const float* __restrict__ te,
                           const float* __restrict__ pe, float* __restrict__ h,
                           const float* __restrict__ g, const float* __restrict__ b,
                           u16* __restrict__ xn) {
    int row = blockIdx.x;
    int t = threadIdx.x;
    int tok = x[row];
    int s = row & 1023;
    float4 a = ((const float4*)(te + (size_t)tok * 1024))[t];
    float4 p = ((const float4*)(pe + (size_t)s * 1024))[t];
    a.x += p.x; a.y += p.y; a.z += p.z; a.w += p.w;
    ((float4*)(h + (size_t)row * 1024))[t] = a;
    ln_store(a, g, b, xn, row, t);
}

__global__ void fuse2ln_k(const float* __restrict__ p0, const float* __restrict__ p1,
                          const float* __restrict__ bias, float* __restrict__ h,
                          const float* __restrict__ g, const float* __restrict__ b,
                          u16* __restrict__ xn) {
    int row = blockIdx.x;
    int t = threadIdx.x;
    size_t idx = (size_t)row * 256 + t;
    float4 a = ((const float4*)p0)[idx];
    float4 bb = ((const float4*)p1)[idx];
    float4 c = ((const float4*)bias)[t];
    float4 v = ((const float4*)h)[idx];
    v.x += a.x + bb.x + c.x;
    v.y += a.y + bb.y + c.y;
    v.z += a.z + bb.z + c.z;
    v.w += a.w + bb.w + c.w;
    ((float4*)h)[idx] = v;
    ln_store(v, g, b, xn, row, t);
}

// ============ 256x256 8-wave 4-phase-per-K-tile GEMM (BK=64, counted vmcnt) ============
template<int PH>
DEV void phase_mma(const bf16x8 (&af)[2][2], const bf16x8 (&bfr)[4][2], f32x4 (&acc)[8][4]) {
    __builtin_amdgcn_s_barrier();
    asm volatile("s_waitcnt lgkmcnt(0)" ::: "memory");
    __builtin_amdgcn_sched_barrier(0);
    __builtin_amdgcn_s_setprio(1);
    #pragma unroll
    for (int ms = 0; ms < 2; ++ms)
        #pragma unroll
        for (int nj = 0; nj < 4; ++nj)
            #pragma unroll
            for (int kk = 0; kk < 2; ++kk)
                acc[PH * 2 + ms][nj] = __builtin_amdgcn_mfma_f32_16x16x32_bf16(
                    af[ms][kk], bfr[nj][kk], acc[PH * 2 + ms][nj], 0, 0, 0);
    __builtin_amdgcn_s_setprio(0);
}

template<int PH>
DEV void read_afrags(const char* Ab, int arow, int fr, int fq, bf16x8 (&af)[2][2]) {
    #pragma unroll
    for (int ms = 0; ms < 2; ++ms)
        #pragma unroll
        for (int kk = 0; kk < 2; ++kk) {
            int lin = (arow + (PH * 2 + ms) * 16 + fr) * 128 + kk * 64 + fq * 16;
            af[ms][kk] = *(const bf16x8*)(Ab + swz(lin));
        }
}

template<int BIAS, int OUTBF>
__global__ __launch_bounds__(512, 2)
void gemm8p(const u16* __restrict__ A, const u16* __restrict__ Bw,
            const float* __restrict__ bias,
            float* __restrict__ outf, u16* __restrict__ outb,
            int M, int N, int K) {
    __shared__ char lds[131072];
    char* ldsA = lds;
    char* ldsB = lds + 65536;
    const int t = threadIdx.x;
    const int w = t >> 6, l = t & 63;
    const int fr = l & 15, fq = l >> 4;
    const int wm = w >> 2, wn = w & 3;

    int bid = blockIdx.y * gridDim.x + blockIdx.x;
    int swzb = xcd_swz(bid, gridDim.x * gridDim.y);
    const int m0 = (swzb % gridDim.x) * 256;
    const int n0 = (swzb / gridDim.x) * 256;
    const int nt = K >> 6;
    const int arow = wm * 128;

    const u16* Asrc = A + (size_t)m0 * K;
    const u16* Bsrc = Bw + (size_t)n0 * K;

    size_t o00, o01, o10, o11;
    {
        int p;
        p = 0 * 16384 + 0 * 8192 + t * 16; o00 = (size_t)(p >> 7) * K + ((swz(p) & 127) >> 1);
        p = 0 * 16384 + 1 * 8192 + t * 16; o01 = (size_t)(p >> 7) * K + ((swz(p) & 127) >> 1);
        p = 1 * 16384 + 0 * 8192 + t * 16; o10 = (size_t)(p >> 7) * K + ((swz(p) & 127) >> 1);
        p = 1 * 16384 + 1 * 8192 + t * 16; o11 = (size_t)(p >> 7) * K + ((swz(p) & 127) >> 1);
    }
    const int wb = w * 1024;

    gload16(Asrc + o00, ldsA + wb);
    gload16(Asrc + o01, ldsA + 8192 + wb);
    gload16(Asrc + o10, ldsA + 16384 + wb);
    gload16(Asrc + o11, ldsA + 16384 + 8192 + wb);
    gload16(Bsrc + o00, ldsB + wb);
    gload16(Bsrc + o01, ldsB + 8192 + wb);
    gload16(Bsrc + o10, ldsB + 16384 + wb);
    gload16(Bsrc + o11, ldsB + 16384 + 8192 + wb);
    gload16(Bsrc + o00 + 64, ldsB + 32768 + wb);
    gload16(Bsrc + o01 + 64, ldsB + 32768 + 8192 + wb);
    gload16(Bsrc + o10 + 64, ldsB + 32768 + 16384 + wb);
    gload16(Bsrc + o11 + 64, ldsB + 32768 + 16384 + 8192 + wb);
    asm volatile("s_waitcnt vmcnt(4)" ::: "memory");
    __builtin_amdgcn_s_barrier();
    __builtin_amdgcn_sched_barrier(0);

    f32x4 acc[8][4] = {};

    for (int T = 0; T < nt; ++T) {
        const char* Ab = ldsA + (T & 1) * 32768;
        const char* Bb = ldsB + (T & 1) * 32768;
        char* Anx = ldsA + ((T + 1) & 1) * 32768;
        char* Bnx = ldsB + (T & 1) * 32768;
        const bool stA = (T + 1 < nt), stB = (T + 2 < nt);
        const size_t kA = (size_t)(T + 1) * 64, kB = (size_t)(T + 2) * 64;

        bf16x8 bfr[4][2], af[2][2];

        #pragma unroll
        for (int nj = 0; nj < 4; ++nj)
            #pragma unroll
            for (int kk = 0; kk < 2; ++kk) {
                int lin = (wn * 64 + nj * 16 + fr) * 128 + kk * 64 + fq * 16;
                bfr[nj][kk] = *(const bf16x8*)(Bb + swz(lin));
            }
        read_afrags<0>(Ab, arow, fr, fq, af);
        if (stA) {
            gload16(Asrc + o00 + kA, Anx + wb);
            gload16(Asrc + o01 + kA, Anx + 8192 + wb);
        }
        phase_mma<0>(af, bfr, acc);
        __builtin_amdgcn_s_barrier();

        read_afrags<1>(Ab, arow, fr, fq, af);
        if (stA) {
            gload16(Asrc + o10 + kA, Anx + 16384 + wb);
            gload16(Asrc + o11 + kA, Anx + 16384 + 8192 + wb);
        }
        phase_mma<1>(af, bfr, acc);
        __builtin_amdgcn_s_barrier();

        read_afrags<2>(Ab, arow, fr, fq, af);
        if (stB) {
            gload16(Bsrc + o00 + kB, Bnx + wb);
            gload16(Bsrc + o01 + kB, Bnx + 8192 + wb);
        }
        phase_mma<2>(af, bfr, acc);
        __builtin_amdgcn_s_barrier();

        read_afrags<3>(Ab, arow, fr, fq, af);
        if (stB) {
            gload16(Bsrc + o10 + kB, Bnx + 16384 + wb);
            gload16(Bsrc + o11 + kB, Bnx + 16384 + 8192 + wb);
        }
        phase_mma<3>(af, bfr, acc);
        if (stB)      asm volatile("s_waitcnt vmcnt(4)" ::: "memory");
        else if (stA) asm volatile("s_waitcnt vmcnt(0)" ::: "memory");
        __builtin_amdgcn_s_barrier();
        __builtin_amdgcn_sched_barrier(0);
    }

    #pragma unroll
    for (int mi = 0; mi < 8; ++mi) {
        #pragma unroll
        for (int nj = 0; nj < 4; ++nj) {
            #pragma unroll
            for (int r = 0; r < 4; ++r) {
                int row = m0 + wm * 128 + mi * 16 + fq * 4 + r;
                int col = n0 + wn * 64 + nj * 16 + fr;
                float v = acc[mi][nj][r];
                if (BIAS) v += bias[col];
                if (OUTBF) outb[(size_t)row * N + col] = f2bf(v);
                else       outf[(size_t)row * N + col] = v;
            }
        }
    }
}

// ============ 128x128 8-wave 2-phase-per-K-tile GEMM (BK=64, counted vmcnt(2)) ============
template<int BIAS, int GELU_, int OUTBF, int SPLITK>
__global__ __launch_bounds__(512, 2)
void gemm4p(const u16* __restrict__ A, const u16* __restrict__ Bw,
            const float* __restrict__ bias,
            float* __restrict__ outf, u16* __restrict__ outb,
            int M, int N, int K) {
    __shared__ char lds[65536];
    char* ldsA = lds;
    char* ldsB = lds + 32768;
    const int t = threadIdx.x;
    const int w = t >> 6, l = t & 63;
    const int fr = l & 15, fq = l >> 4;
    const int wm = w >> 2, wn = w & 3;

    int bid = blockIdx.y * gridDim.x + blockIdx.x;
    int swzb = xcd_swz(bid, gridDim.x * gridDim.y);
    const int m0 = (swzb % gridDim.x) * 128;
    const int n0 = (swzb / gridDim.x) * 128;

    int kbase = 0, Keff = K;
    if (SPLITK) { Keff = K >> 1; kbase = blockIdx.z * Keff; }
    const int nt = Keff >> 6;

    const u16* Asrc = A + (size_t)m0 * K + kbase;
    const u16* Bsrc = Bw + (size_t)n0 * K + kbase;

    size_t o0, o1;
    {
        int p = t * 16;        o0 = (size_t)(p >> 7) * K + ((swz(p) & 127) >> 1);
        p = 8192 + t * 16;     o1 = (size_t)(p >> 7) * K + ((swz(p) & 127) >> 1);
    }
    const int wb = w * 1024;

    gload16(Asrc + o0, ldsA + wb);
    gload16(Asrc + o1, ldsA + 8192 + wb);
    gload16(Bsrc + o0, ldsB + wb);
    gload16(Bsrc + o1, ldsB + 8192 + wb);
    gload16(Bsrc + o0 + 64, ldsB + 16384 + wb);
    gload16(Bsrc + o1 + 64, ldsB + 16384 + 8192 + wb);
    asm volatile("s_waitcnt vmcnt(2)" ::: "memory");
    __builtin_amdgcn_s_barrier();
    __builtin_amdgcn_sched_barrier(0);

    f32x4 acc[4][2] = {};

    for (int T = 0; T < nt; ++T) {
        const char* Ab = ldsA + (T & 1) * 16384;
        const char* Bb = ldsB + (T & 1) * 16384;
        char* Anx = ldsA + ((T + 1) & 1) * 16384;
        char* Bnx = ldsB + (T & 1) * 16384;
        const bool stA = (T + 1 < nt), stB = (T + 2 < nt);
        const size_t kA = (size_t)(T + 1) * 64, kB = (size_t)(T + 2) * 64;

        bf16x8 bfr[2][2], af[2][2];

        #pragma unroll
        for (int nj = 0; nj < 2; ++nj)
            #pragma unroll
            for (int kk = 0; kk < 2; ++kk) {
                int lin = (wn * 32 + nj * 16 + fr) * 128 + kk * 64 + fq * 16;
                bfr[nj][kk] = *(const bf16x8*)(Bb + swz(lin));
            }
        #pragma unroll
        for (int ms = 0; ms < 2; ++ms)
            #pragma unroll
            for (int kk = 0; kk < 2; ++kk) {
                int lin = (wm * 64 + ms * 16 + fr) * 128 + kk * 64 + fq * 16;
                af[ms][kk] = *(const bf16x8*)(Ab + swz(lin));
            }
        if (stA) {
            gload16(Asrc + o0 + kA, Anx + wb);
            gload16(Asrc + o1 + kA, Anx + 8192 + wb);
        }
        __builtin_amdgcn_s_barrier();
        asm volatile("s_waitcnt lgkmcnt(0)" ::: "memory");
        __builtin_amdgcn_sched_barrier(0);
        __builtin_amdgcn_s_setprio(1);
        #pragma unroll
        for (int ms = 0; ms < 2; ++ms)
            #pragma unroll
            for (int nj = 0; nj < 2; ++nj)
                #pragma unroll
                for (int kk = 0; kk < 2; ++kk)
                    acc[ms][nj] = __builtin_amdgcn_mfma_f32_16x16x32_bf16(
                        af[ms][kk], bfr[nj][kk], acc[ms][nj], 0, 0, 0);
        __builtin_amdgcn_s_setprio(0);
        __builtin_amdgcn_s_barrier();

        #pragma unroll
        for (int ms = 0; ms < 2; ++ms)
            #pragma unroll
            for (int kk = 0; kk < 2; ++kk) {
                int lin = (wm * 64 + (2 + ms) * 16 + fr) * 128 + kk * 64 + fq * 16;
                af[ms][kk] = *(const bf16x8*)(Ab + swz(lin));
            }
        if (stB) {
            gload16(Bsrc + o0 + kB, Bnx + wb);
            gload16(Bsrc + o1 + kB, Bnx + 8192 + wb);
        }
        __builtin_amdgcn_s_barrier();
        asm volatile("s_waitcnt lgkmcnt(0)" ::: "memory");
        __builtin_amdgcn_sched_barrier(0);
        __builtin_amdgcn_s_setprio(1);
        #pragma unroll
        for (int ms = 0; ms < 2; ++ms)
            #pragma unroll
            for (int nj = 0; nj < 2; ++nj)
                #pragma unroll
                for (int kk = 0; kk < 2; ++kk)
                    acc[2 + ms][nj] = __builtin_amdgcn_mfma_f32_16x16x32_bf16(
                        af[ms][kk], bfr[nj][kk], acc[2 + ms][nj], 0, 0, 0);
        __builtin_amdgcn_s_setprio(0);
        if (stB)      asm volatile("s_waitcnt vmcnt(2)" ::: "memory");
        else if (stA) asm volatile("s_waitcnt vmcnt(0)" ::: "memory");
        __builtin_amdgcn_s_barrier();
        __builtin_amdgcn_sched_barrier(0);
    }

    float* op = outf;
    if (SPLITK) op = outf + (size_t)blockIdx.z * M * N;

    #pragma unroll
    for (int mi = 0; mi < 4; ++mi) {
        #pragma unroll
        for (int nj = 0; nj < 2; ++nj) {
            #pragma unroll
            for (int r = 0; r < 4; ++r) {
                int row = m0 + wm * 64 + mi * 16 + fq * 4 + r;
                int col = n0 + wn * 32 + nj * 16 + fr;
                float v = acc[mi][nj][r];
                if (BIAS) v += bias[col];
                if (GELU_) v = 0.5f * v * (1.0f + erff(v * 0.70710678118f));
                if (OUTBF) outb[(size_t)row * N + col] = f2bf(v);
                else       op[(size_t)row * N + col] = v;
            }
        }
    }
}

// ---------------- 2-phase double-buffered GEMM (proj: RES epilogue) ----------------
template<int BM, int BN, int BIAS, int GELU_, int RES, int OUTBF, int SPLITK>
__global__ void gemm_db(const u16* __restrict__ A, const u16* __restrict__ Bw,
                        const float* __restrict__ bias, const float* __restrict__ res,
                        float* __restrict__ outf, u16* __restrict__ outb,
                        int M, int N, int K) {
    constexpr int MR = BM / 32;
    constexpr int NR = BN / 32;
    constexpr int AL = BM / 64;
    constexpr int BL = BN / 64;
    __shared__ u16 lA[2][BM * 32];
    __shared__ u16 lB[2][BN * 32];
    const int t = threadIdx.x;
    const int w = t >> 6, l = t & 63;

    int bid = blockIdx.y * gridDim.x + blockIdx.x;
    int swzb = xcd_swz(bid, gridDim.x * gridDim.y);
    const int m0 = (swzb % gridDim.x) * BM;
    const int n0 = (swzb / gridDim.x) * BN;

    int kbase = 0, Keff = K;
    if (SPLITK) { Keff = K >> 1; kbase = blockIdx.z * Keff; }
    const int nt = Keff >> 5;

    const int wr = (w >> 1) * (BM / 2), wc = (w & 1) * (BN / 2);
    const int fr = l & 15, fq = l >> 4;
    const int g0 = w * 64 + l;

    const int srow = g0 >> 2, scol = (g0 & 3) * 8;

    f32x4 acc[MR][NR] = {};

    #pragma unroll
    for (int i = 0; i < AL; ++i)
        gload16(A + (size_t)(m0 + srow + i * 64) * K + kbase + scol, lA[0] + (srow + i * 64) * 32 + scol);
    #pragma unroll
    for (int i = 0; i < BL; ++i)
        gload16(Bw + (size_t)(n0 + srow + i * 64) * K + kbase + scol, lB[0] + (srow + i * 64) * 32 + scol);
    __syncthreads();

    for (int T = 0; T < nt; ++T) {
        const int cur = T & 1, nxt = cur ^ 1;
        if (T + 1 < nt) {
            const int kk = kbase + (T + 1) * 32;
            #pragma unroll
            for (int i = 0; i < AL; ++i)
                gload16(A + (size_t)(m0 + srow + i * 64) * K + kk + scol, lA[nxt] + (srow + i * 64) * 32 + scol);
            #pragma unroll
            for (int i = 0; i < BL; ++i)
                gload16(Bw + (size_t)(n0 + srow + i * 64) * K + kk + scol, lB[nxt] + (srow + i * 64) * 32 + scol);
        }
        bf16x8 af[MR], bfv[NR];
        #pragma unroll
        for (int mi = 0; mi < MR; ++mi)
            af[mi] = *(const bf16x8*)(lA[cur] + (wr + mi * 16 + fr) * 32 + fq * 8);
        #pragma unroll
        for (int ni = 0; ni < NR; ++ni)
            bfv[ni] = *(const bf16x8*)(lB[cur] + (wc + ni * 16 + fr) * 32 + fq * 8);
        #pragma unroll
        for (int mi = 0; mi < MR; ++mi)
            #pragma unroll
            for (int ni = 0; ni < NR; ++ni)
                acc[mi][ni] = __builtin_amdgcn_mfma_f32_16x16x32_bf16(af[mi], bfv[ni], acc[mi][ni], 0, 0, 0);
        __syncthreads();
    }

    float* op = outf;
    if (SPLITK) op = outf + (size_t)blockIdx.z * M * N;

    #pragma unroll
    for (int mi = 0; mi < MR; ++mi) {
        #pragma unroll
        for (int ni = 0; ni < NR; ++ni) {
            #pragma unroll
            for (int r = 0; r < 4; ++r) {
                int row = m0 + wr + mi * 16 + fq * 4 + r;
                int col = n0 + wc + ni * 16 + fr;
                float v = acc[mi][ni][r];
                if (BIAS) v += bias[col];
                if (GELU_) v = 0.5f * v * (1.0f + erff(v * 0.70710678118f));
                if (RES) v += res[(size_t)row * N + col];
                if (OUTBF) outb[(size_t)row * N + col] = f2bf(v);
                else       op[(size_t)row * N + col] = v;
            }
        }
    }
}

// ---------------- Flash attention: QBLK=128, 8 waves, K/V double-buffer, defer-max ----------------
__global__ __launch_bounds__(512, 2)
void attn_k(const u16* __restrict__ qkv, u16* __restrict__ o) {
    __shared__ u16 lK[2][64 * 64];     // 16 KB dbuf
    __shared__ u16 lV[2][64 * 64];     // 16 KB dbuf, transposed [d][kv], swizzled
    __shared__ u16 lP[8 * 16 * 64];    // 16 KB per-wave
    const int t = threadIdx.x;
    const int w = t >> 6, l = t & 63;
    const int fr = l & 15, fq = l >> 4;

    int swzb = xcd_swz(blockIdx.x, gridDim.x);
    const int qb = 7 - (swzb & 7);
    const int hh = (swzb >> 3) & 15;
    const int b  = swzb >> 7;
    const int q0 = qb * 128;
    const int qw = q0 + w * 16;

    const u16* srcK;
    {
        int p = t * 16;
        int L = swz(p);
        srcK = qkv + ((size_t)(b * 1024) + (L >> 7)) * 3072 + 1024 + hh * 64 + ((L & 127) >> 1);
    }

    const int kvp = (t & 31) * 2;
    const int vd0 = (t >> 5) * 4;
    const u16* srcV = qkv + (size_t)(b * 1024) * 3072 + 2048 + hh * 64 + vd0;

    bf16x8 qf[2];
    {
        size_t base = ((size_t)(b * 1024) + qw + fr) * 3072 + hh * 64;
        qf[0] = *(const bf16x8*)(qkv + base + fq * 8);
        qf[1] = *(const bf16x8*)(qkv + base + 32 + fq * 8);
    }

    float m_run[4], l_run[4];
    f32x4 acc_o[4] = {};
    #pragma unroll
    for (int r = 0; r < 4; ++r) { m_run[r] = -__builtin_inff(); l_run[r] = 0.0f; }

    // prologue: stage tile 0 into buffer 0
    uint2 gv0 = *(const uint2*)(srcV + (size_t)kvp * 3072);
    uint2 gv1 = *(const uint2*)(srcV + (size_t)(kvp + 1) * 3072);
    gload16(srcK, (char*)lK[0] + w * 1024);
    #pragma unroll
    for (int j = 0; j < 4; ++j) {
        u32 lo = (j < 2) ? gv0.x : gv0.y;
        u32 hi = (j < 2) ? gv1.x : gv1.y;
        lo = (j & 1) ? (lo >> 16) : (lo & 0xffffu);
        hi = (j & 1) ? (hi >> 16) : (hi & 0xffffu);
        u32 word = lo | (hi << 16);
        int pv = (vd0 + j) * 128 + kvp * 2;
        *(u32*)((char*)lV[0] + swz(pv)) = word;
    }

    const int kv_end = q0 + 128;
    int cur = 0;
    for (int kv0 = 0; kv0 < kv_end; kv0 += 64, cur ^= 1) {
        __syncthreads();   // buffer[cur] staged (drains prev gload + V writes); prev reads done
        const int nxt = cur ^ 1;
        const bool more = (kv0 + 64 < kv_end);
        if (more) {
            gload16(srcK + (size_t)(kv0 + 64) * 3072, (char*)lK[nxt] + w * 1024);
            gv0 = *(const uint2*)(srcV + (size_t)(kv0 + 64 + kvp) * 3072);
            gv1 = *(const uint2*)(srcV + (size_t)(kv0 + 64 + kvp + 1) * 3072);
        }

        const bool active = (kv0 <= qw + 15);   // wave-uniform
        if (active) {
            f32x4 accs[4] = {};
            #pragma unroll
            for (int nt = 0; nt < 4; ++nt) {
                #pragma unroll
                for (int ks = 0; ks < 2; ++ks) {
                    int pk = ((nt * 16 + fr) * 64 + ks * 32 + fq * 8) * 2;
                    bf16x8 kf = *(const bf16x8*)((const char*)lK[cur] + swz(pk));
                    accs[nt] = __builtin_amdgcn_mfma_f32_16x16x32_bf16(qf[ks], kf, accs[nt], 0, 0, 0);
                }
            }

            float p[4][4], mx[4], rs[4];
            #pragma unroll
            for (int r = 0; r < 4; ++r) {
                int qg = qw + fq * 4 + r;
                float m = -__builtin_inff();
                #pragma unroll
                for (int nt = 0; nt < 4; ++nt) {
                    int kvg = kv0 + nt * 16 + fr;
                    float s = (kvg <= qg) ? accs[nt][r] * 0.125f : -__builtin_inff();
                    p[nt][r] = s;
                    m = fmaxf(m, s);
                }
                mx[r] = m;
            }
            #pragma unroll
            for (int msk = 1; msk < 16; msk <<= 1) {
                #pragma unroll
                for (int r = 0; r < 4; ++r) mx[r] = fmaxf(mx[r], __shfl_xor(mx[r], msk));
            }

            // T13 defer-max: skip rescale when tile max is within 8 of running max
            bool need = false;
            #pragma unroll
            for (int r = 0; r < 4; ++r) need |= (mx[r] > m_run[r] + 8.0f);
            if (__any(need)) {
                float mnew[4], alpha[4];
                #pragma unroll
                for (int r = 0; r < 4; ++r) {
                    mnew[r] = fmaxf(m_run[r], mx[r]);
                    alpha[r] = __expf(m_run[r] - mnew[r]);
                    float s = 0.0f;
                    #pragma unroll
                    for (int nt = 0; nt < 4; ++nt) {
                        float pv = __expf(p[nt][r] - mnew[r]);
                        p[nt][r] = pv;
                        s += pv;
                    }
                    rs[r] = s;
                }
                #pragma unroll
                for (int msk = 1; msk < 16; msk <<= 1) {
                    #pragma unroll
                    for (int r = 0; r < 4; ++r) rs[r] += __shfl_xor(rs[r], msk);
                }
                #pragma unroll
                for (int r = 0; r < 4; ++r) {
                    l_run[r] = l_run[r] * alpha[r] + rs[r];
                    m_run[r] = mnew[r];
                }
                #pragma unroll
                for (int nt = 0; nt < 4; ++nt)
                    #pragma unroll
                    for (int r = 0; r < 4; ++r) acc_o[nt][r] *= alpha[r];
            } else {
                #pragma unroll
                for (int r = 0; r < 4; ++r) {
                    float s = 0.0f;
                    #pragma unroll
                    for (int nt = 0; nt < 4; ++nt) {
                        float pv = __expf(p[nt][r] - m_run[r]);
                        p[nt][r] = pv;
                        s += pv;
                    }
                    rs[r] = s;
                }
                #pragma unroll
                for (int msk = 1; msk < 16; msk <<= 1) {
                    #pragma unroll
                    for (int r = 0; r < 4; ++r) rs[r] += __shfl_xor(rs[r], msk);
                }
                #pragma unroll
                for (int r = 0; r < 4; ++r) l_run[r] += rs[r];
            }

            #pragma unroll
            for (int nt = 0; nt < 4; ++nt)
                #pragma unroll
                for (int r = 0; r < 4; ++r) {
                    int pp = (w * 1024 + (fq * 4 + r) * 64 + nt * 16 + fr) * 2;
                    *(u16*)((char*)lP + swz(pp)) = f2bf(p[nt][r]);
                }

            bf16x8 pa[2];
            #pragma unroll
            for (int ks = 0; ks < 2; ++ks) {
                int ppr = (w * 1024 + fr * 64 + ks * 32 + fq * 8) * 2;
                pa[ks] = *(const bf16x8*)((const char*)lP + swz(ppr));
            }
            #pragma unroll
            for (int nt = 0; nt < 4; ++nt) {
                #pragma unroll
                for (int ks = 0; ks < 2; ++ks) {
                    int pvr = ((nt * 16 + fr) * 64 + ks * 32 + fq * 8) * 2;
                    bf16x8 vf = *(const bf16x8*)((const char*)lV[cur] + swz(pvr));
                    acc_o[nt] = __builtin_amdgcn_mfma_f32_16x16x32_bf16(pa[ks], vf, acc_o[nt], 0, 0, 0);
                }
            }
        }

        // write V(t+1) regs -> lV[nxt] (safe: nxt buffer's readers finished before top-of-loop sync)
        if (more) {
            #pragma unroll
            for (int j = 0; j < 4; ++j) {
                u32 lo = (j < 2) ? gv0.x : gv0.y;
                u32 hi = (j < 2) ? gv1.x : gv1.y;
                lo = (j & 1) ? (lo >> 16) : (lo & 0xffffu);
                hi = (j & 1) ? (hi >> 16) : (hi & 0xffffu);
                u32 word = lo | (hi << 16);
                int pv = (vd0 + j) * 128 + kvp * 2;
                *(u32*)((char*)lV[nxt] + swz(pv)) = word;
            }
        }
    }

    #pragma unroll
    for (int nt = 0; nt < 4; ++nt) {
        #pragma unroll
        for (int r = 0; r < 4; ++r) {
            int qg = qw + fq * 4 + r;
            int d = nt * 16 + fr;
            float ov = acc_o[nt][r] / l_run[r];
            o[((size_t)(b * 1024) + qg) * 1024 + hh * 64 + d] = f2bf(ov);
        }
    }
}

// ---------------- launch ----------------
extern "C" void kernel_launch(void* const* d_in, const int* in_sizes, int n_in,
                              void* d_out, int out_size, void* d_ws, size_t ws_size,
                              hipStream_t stream) {
    const int*   x       = (const int*)  d_in[0];
    const float* tok_emb = (const float*)d_in[1];
    const float* pos_emb = (const float*)d_in[2];
    const float* ln1_g   = (const float*)d_in[3];
    const float* ln1_b   = (const float*)d_in[4];
    const float* qkv_w   = (const float*)d_in[5];
    const float* qkv_b   = (const float*)d_in[6];
    const float* proj_w  = (const float*)d_in[7];
    const float* proj_b  = (const float*)d_in[8];
    const float* ln2_g   = (const float*)d_in[9];
    const float* ln2_b   = (const float*)d_in[10];
    const float* fc1_w   = (const float*)d_in[11];
    const float* fc1_b   = (const float*)d_in[12];
    const float* fc2_w   = (const float*)d_in[13];
    const float* fc2_b   = (const float*)d_in[14];
    const float* lnf_g   = (const float*)d_in[15];
    const float* lnf_b   = (const float*)d_in[16];
    const float* head_w  = (const float*)d_in[17];
    float* out = (float*)d_out;

    char* ws = (char*)d_ws;
    float* h   = (float*)(ws + 0);            //  8 MB f32 (2048x1024)
    u16*   xn  = (u16*)(ws + 8388608);        //  4 MB bf16
    u16*   qkv = (u16*)(ws + 12582912);       // 12.6 MB bf16 (2048x3072)
    u16*   ob  = (u16*)(ws + 25165824);       //  4 MB bf16
    u16*   ff  = (u16*)(ws + 29360128);       // 16.8 MB bf16 (2048x4096)
    u16*   wq  = (u16*)(ws + 46137344);       // 65.5 MB bf16 weight slab
    float* pbuf = (float*)(ws + 12582912);    // fc2 split-K partials (dead region)

    u16* wqkv = wq;
    u16* wproj = wqkv + 3072 * 1024;
    u16* wfc1  = wproj + 1024 * 1024;
    u16* wfc2  = wfc1 + 4096 * 1024;

    const int M = 2048;

    embed_ln_k<<<dim3(2048), 256, 0, stream>>>(x, tok_emb, pos_emb, h, ln1_g, ln1_b, xn);

    for (int lyr = 0; lyr < 6; ++lyr) {
        cvt4_k<<<dim3(2048), 256, 0, stream>>>(
            qkv_w + (size_t)lyr * 3072 * 1024, proj_w + (size_t)lyr * 1024 * 1024,
            fc1_w + (size_t)lyr * 4096 * 1024, fc2_w + (size_t)lyr * 1024 * 4096,
            wq, 3072 * 256, 1024 * 256, 4096 * 256, 4096 * 256);
        gemm4p<1, 0, 1, 0><<<dim3(16, 24), 512, 0, stream>>>(
            xn, wqkv, qkv_b + lyr * 3072, nullptr, qkv, M, 3072, 1024);
        attn_k<<<dim3(256), 512, 0, stream>>>(qkv, ob);
        gemm_db<64, 64, 1, 0, 1, 0, 0><<<dim3(32, 16), 256, 0, stream>>>(
            ob, wproj, proj_b + lyr * 1024, h, h, nullptr, M, 1024, 1024);
        ln_k<<<dim3(2048), 256, 0, stream>>>(h, ln2_g + lyr * 1024, ln2_b + lyr * 1024, xn);
        gemm4p<1, 1, 1, 0><<<dim3(16, 32), 512, 0, stream>>>(
            xn, wfc1, fc1_b + lyr * 4096, nullptr, ff, M, 4096, 1024);
        gemm4p<0, 0, 0, 1><<<dim3(16, 8, 2), 512, 0, stream>>>(
            ff, wfc2, nullptr, pbuf, nullptr, M, 1024, 4096);
        const float* g = (lyr < 5) ? (ln1_g + (lyr + 1) * 1024) : lnf_g;
        const float* b = (lyr < 5) ? (ln1_b + (lyr + 1) * 1024) : lnf_b;
        fuse2ln_k<<<dim3(2048), 256, 0, stream>>>(
            pbuf, pbuf + (size_t)M * 1024, fc2_b + lyr * 1024, h, g, b, xn);
    }

    cvt_k<<<dim3(2048), 256, 0, stream>>>(head_w, wq, 32000 * 1024 / 4);
    gemm8p<0, 0><<<dim3(8, 125), 512, 0, stream>>>(
        xn, wq, nullptr, out, nullptr, M, 32000, 1024);
}